// Round 6
// baseline (370.712 us; speedup 1.0000x reference)
//
#include <hip/hip_runtime.h>
#include <hip/hip_bf16.h>
#include <stdint.h>

typedef short short8 __attribute__((ext_vector_type(8)));
typedef float f32x4 __attribute__((ext_vector_type(4)));

#define KKTOT 2304   // 9*256
#define PXS   40     // padded LDS row stride (elements)

__device__ __forceinline__ short f2bf(float f) {
    __hip_bfloat16 h = __float2bfloat16(f);
    return __builtin_bit_cast(short, h);
}

// ---- prep 1a: K2(ci,co) = sum_p kernel[p,ci,co]^2 --------------------------
__global__ void prep_k2(const float* __restrict__ kern, float* __restrict__ K2)
{
    const int ci = blockIdx.x, co = threadIdx.x;
    float acc = 0.f;
#pragma unroll
    for (int p = 0; p < 9; ++p) {
        float w = kern[(p * 256 + ci) * 256 + co];
        acc += w * w;
    }
    K2[ci * 256 + co] = acc;
}

// ---- prep 1b: demod(b,co) = 1/sqrt( sum_ci style^2 * K2 + eps ) ------------
__global__ void prep_demod(const float* __restrict__ style,
                           const float* __restrict__ K2,
                           float* __restrict__ demod)
{
    const int b = blockIdx.x, co = threadIdx.x;
    __shared__ float s2[256];
    float s = style[b * 256 + co];
    s2[co] = s * s;
    __syncthreads();
    float acc = 0.f;
#pragma unroll 8
    for (int ci = 0; ci < 256; ++ci)
        acc += s2[ci] * K2[ci * 256 + co];
    demod[b * 256 + co] = 1.0f / sqrtf(acc + 1e-7f);
}

// ---- prep 2: kT(co, kidx) = bf16(kernel[kidx][co]) -------------------------
__global__ void prep_kt(const float* __restrict__ kern,
                        __hip_bfloat16* __restrict__ kT)
{
    __shared__ float tile[64][65];
    const int t   = threadIdx.x;
    const int k0  = blockIdx.x << 6;
    const int c0  = blockIdx.y << 6;
    const int col = t & 63;
    const int rb  = (t >> 6) << 4;
#pragma unroll
    for (int r = 0; r < 16; ++r) {
        int kl = rb + r;
        tile[kl][col] = kern[(size_t)(k0 + kl) * 256 + c0 + col];
    }
    __syncthreads();
#pragma unroll
    for (int r = 0; r < 16; ++r) {
        int co = rb + r;
        kT[(size_t)(c0 + co) * KKTOT + k0 + col] = __float2bfloat16(tile[col][co]);
    }
}

// ---- main: implicit-GEMM conv, BM=256 (2 h-rows) x BN=128, bf16 MFMA -------
// 1024 blocks. Per slice (dh x cin-chunk of 32): stage 2 unshifted x rows
// (f32->bf16, style folded) into haloed buffers + 3 B taps; 384 MFMA per
// barrier-pair. Wave w: output row j=w>>1, cout half ch=w&1; acc 8x4 tiles.
// Invalid boundary rows zero-filled (rare). Demod in f32 epilogue.
__global__ __launch_bounds__(256, 2) void conv_mfma(
    const float* __restrict__ x,
    const __hip_bfloat16* __restrict__ kt,
    const float* __restrict__ style,
    const float* __restrict__ demod,
    float* __restrict__ out)
{
    __shared__ __align__(16) __hip_bfloat16 Xs[2][130 * PXS];    // 20.8 KB
    __shared__ __align__(16) __hip_bfloat16 Bs[3][128 * PXS];    // 30.7 KB
    __shared__ float Ss[256];
    __shared__ float Ds[128];

    const int t   = threadIdx.x;
    const int bid = blockIdx.x;
    // XCD-contiguous work id: 128 consecutive vids per XCD = 8 hh x 8 b x 2 n0
    const int vid = ((bid & 7) << 7) | (bid >> 3);
    const int n0  = (vid & 1) << 7;
    const int b   = (vid >> 1) & 7;
    const int h0  = (vid >> 4) << 1;            // 0,2,...,126

    const int wave = t >> 6, lane = t & 63;
    const int j    = wave >> 1;                 // output row within block
    const int ch   = wave & 1;                  // cout half (64)
    const int l15  = lane & 15, lk = lane >> 4;

    const int p    = t >> 1;                    // A staging pixel 0..127
    const int ck   = (t & 1) << 4;              // A staging elem offset 0/16
    const int mB   = t >> 2;                    // B staging row 0..63
    const int kofB = (t & 3) << 3;              // B staging elem offset

    if (t < 128) {
        ((float2*)Ss)[t] = ((const float2*)(style + b * 256))[t];
        Ds[t] = demod[b * 256 + n0 + t];
    }
    if (t < 64) {                               // halo rows of both Xs buffers
        int jh = t >> 5, i2 = t & 31;
        Xs[jh][i2]             = __float2bfloat16(0.f);
        Xs[jh][129 * PXS + i2] = __float2bfloat16(0.f);
    }

    f32x4 acc[8][4] = {};

    for (int sl = 0; sl < 24; ++sl) {
        const int dh      = (sl >> 3) - 1;
        const int ci0     = (sl & 7) << 5;
        const int posbase = (sl >> 3) * 3;

        __syncthreads();                        // prior readers done

        // ---- stage A: 2 x-rows, modulate by style, f32 -> bf16 ----
        float4 sv0 = *(const float4*)&Ss[ci0 + ck];
        float4 sv1 = *(const float4*)&Ss[ci0 + ck + 4];
        float4 sv2 = *(const float4*)&Ss[ci0 + ck + 8];
        float4 sv3 = *(const float4*)&Ss[ci0 + ck + 12];
#pragma unroll
        for (int jj2 = 0; jj2 < 2; ++jj2) {
            const int r = h0 + jj2 + dh;
            short8 m0, m1;
            if ((unsigned)r < 128u) {
                const float* g = x + ((size_t)((b * 128 + r) * 128 + p)) * 256 + ci0 + ck;
                float4 v0 = *(const float4*)g;
                float4 v1 = *(const float4*)(g + 4);
                float4 v2 = *(const float4*)(g + 8);
                float4 v3 = *(const float4*)(g + 12);
#pragma unroll
                for (int q = 0; q < 4; ++q) {
                    m0[q]     = f2bf((&v0.x)[q] * (&sv0.x)[q]);
                    m0[q + 4] = f2bf((&v1.x)[q] * (&sv1.x)[q]);
                    m1[q]     = f2bf((&v2.x)[q] * (&sv2.x)[q]);
                    m1[q + 4] = f2bf((&v3.x)[q] * (&sv3.x)[q]);
                }
            } else {
                m0 = short8{}; m1 = short8{};
            }
            *(short8*)&Xs[jj2][(p + 1) * PXS + ck]     = m0;
            *(short8*)&Xs[jj2][(p + 1) * PXS + ck + 8] = m1;
        }

        // ---- stage B: 3 taps of transposed bf16 kernel ----
        const __hip_bfloat16* gw =
            kt + (size_t)(n0 + mB) * KKTOT + posbase * 256 + ci0 + kofB;
#pragma unroll
        for (int tp = 0; tp < 3; ++tp) {
            short8 w0 = *(const short8*)(gw + tp * 256);
            short8 w1 = *(const short8*)(gw + tp * 256 + 64 * KKTOT);
            *(short8*)&Bs[tp][mB * PXS + kofB]        = w0;
            *(short8*)&Bs[tp][(mB + 64) * PXS + kofB] = w1;
        }
        __syncthreads();

        // ---- MFMA: 3 taps x 8x4 tiles per wave ----
#pragma unroll
        for (int tp = 0; tp < 3; ++tp) {        // dw=tp-1; pixel m reads row m+tp
            short8 bf[4];
#pragma unroll
            for (int jj = 0; jj < 4; ++jj)
                bf[jj] = *(const short8*)&Bs[tp][(ch * 64 + jj * 16 + l15) * PXS + lk * 8];
#pragma unroll
            for (int i = 0; i < 8; ++i) {
                short8 af = *(const short8*)&Xs[j][(i * 16 + l15 + tp) * PXS + lk * 8];
#pragma unroll
                for (int jj = 0; jj < 4; ++jj)
                    acc[i][jj] = __builtin_amdgcn_mfma_f32_16x16x32_bf16(
                        af, bf[jj], acc[i][jj], 0, 0, 0);
            }
        }
    }

    // ---- epilogue: demod + f32 store (C/D: col=lane&15, row=(lane>>4)*4+r) -
    float dj[4];
#pragma unroll
    for (int jj = 0; jj < 4; ++jj) dj[jj] = Ds[ch * 64 + jj * 16 + l15];
    const size_t obase = ((size_t)(b * 128 + h0 + j) * 128) * 256 + n0;
#pragma unroll
    for (int i = 0; i < 8; ++i) {
#pragma unroll
        for (int jj = 0; jj < 4; ++jj) {
            const int n = ch * 64 + jj * 16 + l15;
#pragma unroll
            for (int r = 0; r < 4; ++r) {
                const int m = i * 16 + lk * 4 + r;
                out[obase + (size_t)m * 256 + n] = acc[i][jj][r] * dj[jj];
            }
        }
    }
}

extern "C" void kernel_launch(void* const* d_in, const int* in_sizes, int n_in,
                              void* d_out, int out_size, void* d_ws, size_t ws_size,
                              hipStream_t stream)
{
    const float* x     = (const float*)d_in[0];
    const float* style = (const float*)d_in[1];
    const float* kern  = (const float*)d_in[2];
    float* out = (float*)d_out;

    char*  ws    = (char*)d_ws;
    float* demod = (float*)ws;                           // 2048 f32   (8 KB)
    float* K2    = (float*)(ws + 8192);                  // 65536 f32  (256 KB)
    __hip_bfloat16* kT = (__hip_bfloat16*)(ws + 270336); // 589824 bf16 (1.18 MB)

    prep_k2   <<<256, 256, 0, stream>>>(kern, K2);
    prep_demod<<<8,   256, 0, stream>>>(style, K2, demod);
    prep_kt   <<<dim3(36, 4), 256, 0, stream>>>(kern, kT);
    conv_mfma <<<1024, 256, 0, stream>>>(x, kT, style, demod, out);
}